// Round 6
// baseline (18339.894 us; speedup 1.0000x reference)
//
#include <hip/hip_runtime.h>

#define B 8
#define N 8192
#define S 2048
#define K 32
#define NPART 4                  // blocks (CUs) per batch
#define TPB 512                  // 8 waves per block
#define PPT (N / (NPART * TPB))  // 4 contiguous points per thread

// Exact (no-FMA, left-to-right) squared distance to match numpy/XLA fp32:
// ((dx*dx + dy*dy) + dz*dz). FPS argmax is a chaotic recurrence; any ulp
// difference can diverge the selected-center sequence. Verified absmax==0 (R1-R5).
__device__ __forceinline__ float sqdist3(float ax, float ay, float az,
                                         float bx, float by, float bz) {
    float dx = ax - bx, dy = ay - by, dz = az - bz;
    return __fadd_rn(__fadd_rn(__fmul_rn(dx, dx), __fmul_rn(dy, dy)),
                     __fmul_rn(dz, dz));
}

template <int CTRL>
__device__ __forceinline__ float dpp_fmax(float v) {
    const int iv = __float_as_int(v);
    const int sh = __builtin_amdgcn_update_dpp(iv, iv, CTRL, 0xF, 0xF, false);
    return fmaxf(v, __int_as_float(sh));
}
__device__ __forceinline__ float wave_fmax_dpp(float v) {
    v = dpp_fmax<0x111>(v);  // row_shr:1
    v = dpp_fmax<0x112>(v);  // row_shr:2
    v = dpp_fmax<0x114>(v);  // row_shr:4
    v = dpp_fmax<0x118>(v);  // row_shr:8
    v = dpp_fmax<0x142>(v);  // row_bcast:15
    v = dpp_fmax<0x143>(v);  // row_bcast:31 -> lane 63 = wave max
    return __int_as_float(__builtin_amdgcn_readlane(__float_as_int(v), 63));
}
template <int CTRL>
__device__ __forceinline__ unsigned dpp_umax(unsigned v) {
    const int sh = __builtin_amdgcn_update_dpp((int)v, (int)v, CTRL, 0xF, 0xF, false);
    const unsigned u = (unsigned)sh;
    return v > u ? v : u;
}
__device__ __forceinline__ unsigned wave_umax_dpp(unsigned v) {
    v = dpp_umax<0x111>(v);
    v = dpp_umax<0x112>(v);
    v = dpp_umax<0x114>(v);
    v = dpp_umax<0x118>(v);
    v = dpp_umax<0x142>(v);
    v = dpp_umax<0x143>(v);
    return (unsigned)__builtin_amdgcn_readlane((int)v, 63);
}

// ---------------------------------------------------------------------------
// FPS, multi-CU: 4 blocks per batch (32 blocks total), 512 thr, 4 contiguous
// points/thread. NO barriers in the step loop; cross-block sync is a
// step-tagged slot array in global memory (L2), parity double-buffered:
//   key = (step:11)<<53 | (dist_bits:32)<<21 | (8191-gid):13
// Every wave publishes its wave-winner key (agent-scope release store) and
// polls all 32 slots of the batch (lane i <- slot i&31, coalesced, agent-scope
// acquire loads -> L1 bypassed, no stale-spin). u64 max over same-step keys ==
// (max dist, then min gid) == reference argmax order. Winner coords come from
// the immutable xyz[] (broadcast L2 load) -> no coords in the protocol.
// Parity-slot reuse is safe: a wave reaches step s+2 only after every wave
// published s+1, which requires every wave finished polling step s.
// blockIdx mapping: b = blockIdx&7, part = blockIdx>>3 -> a batch's 4 blocks
// land on one XCD under the %8 round-robin dispatch heuristic (L2 locality
// only; agent-scope atomics keep it correct regardless).
// Slots (d_ws): [B][2][32] u64 = 4 KB, zeroed by hipMemsetAsync pre-launch
// (tag 0 != any step >= 1; 0xAA poison would alias step 1365).
// ---------------------------------------------------------------------------
__global__ __launch_bounds__(TPB, 2) void fps_kernel(const float* __restrict__ xyz,
                                                     float* __restrict__ centers,
                                                     unsigned long long* __restrict__ slots) {
    const int b    = blockIdx.x & 7;
    const int part = blockIdx.x >> 3;          // 0..3
    const int t = threadIdx.x;
    const int lane = t & 63;
    const int gwave = (part << 3) | (t >> 6);  // 0..31: wave id within batch
    const float* xb = xyz + (size_t)b * N * 3;
    unsigned long long* sl = slots + (size_t)b * 64;   // [parity][32]

    // 4 contiguous points per thread: gid = (part*512 + t)*4 + i
    const int base = (part * TPB + t) * PPT;
    float x[PPT], y[PPT], z[PPT], md[PPT];
    {
        float raw[3 * PPT];
        const float4* src = (const float4*)(xb + 3 * base);
#pragma unroll
        for (int i = 0; i < 3 * PPT / 4; ++i) {
            const float4 v = src[i];
            raw[4 * i + 0] = v.x; raw[4 * i + 1] = v.y;
            raw[4 * i + 2] = v.z; raw[4 * i + 3] = v.w;
        }
#pragma unroll
        for (int i = 0; i < PPT; ++i) {
            x[i] = raw[3 * i + 0];
            y[i] = raw[3 * i + 1];
            z[i] = raw[3 * i + 2];
            md[i] = INFINITY;
        }
    }

    __shared__ float cent[S * 3];   // center staging (part-0 block uses it)

    // step 0: reference always picks point 0
    float px = xb[0], py = xb[1], pz = xb[2];
    if (part == 0 && t == 0) { cent[0] = px; cent[1] = py; cent[2] = pz; }

    for (int s = 1; s < S; ++s) {
        // --- local update + tracked argmax (strict >, ascending i => first idx)
        float best = -INFINITY;
        int bi = 0;
#pragma unroll
        for (int i = 0; i < PPT; ++i) {
            const float d = sqdist3(x[i], y[i], z[i], px, py, pz);
            const float m = fminf(md[i], d);
            md[i] = m;
            if (m > best) { best = m; bi = i; }
        }

        // --- wave winner (DPP max + ballot first-lane == lowest gid)
        const float wmax = wave_fmax_dpp(best);
        const unsigned long long mb = __ballot(best == wmax);
        const int ol = (int)__builtin_ctzll(mb);

        // --- owner lane publishes step-tagged key (release, agent scope)
        if (lane == ol) {
            const unsigned gid = (unsigned)(base + bi);
            const unsigned long long key =
                ((unsigned long long)s << 53) |
                ((unsigned long long)__float_as_uint(wmax) << 21) |
                (unsigned long long)(8191u - gid);
            __hip_atomic_store(&sl[(s & 1) * 32 + gwave], key,
                               __ATOMIC_RELEASE, __HIP_MEMORY_SCOPE_AGENT);
        }

        // --- poll all 32 batch slots (lane i <- slot i&31; coalesced 256 B)
        unsigned long long k;
        {
            unsigned long long* p = &sl[(s & 1) * 32 + (lane & 31)];
            do {
                k = __hip_atomic_load(p, __ATOMIC_ACQUIRE, __HIP_MEMORY_SCOPE_AGENT);
            } while (__ballot((unsigned)(k >> 53) == (unsigned)s) != ~0ULL);
        }

        // --- reduce 32 keys (duplicated across 64 lanes): max dist, then
        //     max (8191-gid) = min gid. Exact reference tie-break.
        const float dl = __uint_as_float((unsigned)(k >> 21));
        const float dmax = wave_fmax_dpp(dl);
        unsigned rev = (dl == dmax) ? (unsigned)(k & 0x1FFFFFu) : 0u;
        rev = wave_umax_dpp(rev);
        const int win = 8191 - (int)rev;

        // --- winner coords from immutable input (broadcast, L2-hot)
        const float* wp = xb + 3 * win;
        px = wp[0]; py = wp[1]; pz = wp[2];

        if (part == 0 && t == 0) {
            cent[3 * s + 0] = px;
            cent[3 * s + 1] = py;
            cent[3 * s + 2] = pz;
        }
    }

    // --- part-0 block dumps centers coalesced (S*3 = 6144 = 512*12)
    if (part == 0) {
        __syncthreads();
        float* cb = centers + (size_t)b * S * 3;
#pragma unroll
        for (int j = 0; j < (S * 3) / TPB; ++j) {
            const int idx = t + TPB * j;
            cb[idx] = cent[idx];
        }
    }
}

// ---------------------------------------------------------------------------
// KNN + gather: one wave per center. Top-32 held SORTED across lanes 0..31 as
// packed u64 (dist_bits<<32 | idx) -> lexicographic (d, idx) order == stable
// top_k tie semantics. Insert = wave-wide shfl_up shift (O(1) per insert).
// ---------------------------------------------------------------------------
__global__ __launch_bounds__(256) void knn_kernel(const float* __restrict__ xyz,
                                                  const float* __restrict__ centers,
                                                  float* __restrict__ out) {
    const int gw = (int)((blockIdx.x * blockDim.x + threadIdx.x) >> 6);
    const int lane = (int)(threadIdx.x & 63);
    const int b = gw >> 11;        // gw / S
    const int s = gw & (S - 1);
    const float* xb = xyz + (size_t)b * N * 3;
    const float* c = centers + (size_t)(b * S + s) * 3;
    const float cx = c[0], cy = c[1], cz = c[2];

    unsigned long long P = ~0ULL;     // lanes 0..31: sorted top-32 (asc)
    unsigned long long tau = ~0ULL;   // current worst kept = P at lane 31

    for (int i = 0; i < N / 64; ++i) {
        const int p = (i << 6) + lane;
        const float* q = xb + 3 * p;
        const float d = sqdist3(q[0], q[1], q[2], cx, cy, cz);
        const unsigned long long cand =
            ((unsigned long long)__float_as_uint(d) << 32) | (unsigned)p;
        bool alive = cand < tau;
        unsigned long long mask = __ballot(alive);
        while (mask) {
            const int src = __builtin_ctzll(mask);
            const unsigned long long bc = __shfl(cand, src);
            unsigned long long up = __shfl_up(P, 1);
            if (lane == 0) up = bc;
            const bool gt = P > bc;  // strict: bc < tau guarantees lane31 evicts
            const unsigned long long shifted = (up > bc) ? up : bc;
            P = gt ? shifted : P;
            tau = __shfl(P, 31);
            if (lane == src) alive = false;
            alive = alive && (cand < tau);
            mask = __ballot(alive);
        }
    }

    // epilogue: lane k = k-th nearest (ascending d, ties by index = top_k order)
    if (lane < K) {
        const unsigned nidx = (unsigned)P;
        const float* q = xb + 3 * nidx;
        float* o = out + ((size_t)(b * S + s) * K + lane) * 3;
        o[0] = q[0] - cx;
        o[1] = q[1] - cy;
        o[2] = q[2] - cz;
    }
}

extern "C" void kernel_launch(void* const* d_in, const int* in_sizes, int n_in,
                              void* d_out, int out_size, void* d_ws, size_t ws_size,
                              hipStream_t stream) {
    const float* xyz = (const float*)d_in[0];
    float* out = (float*)d_out;                         // neighborhood [B,S,K,3]
    float* centers = out + (size_t)B * S * K * 3;       // centers [B,S,3]
    unsigned long long* slots = (unsigned long long*)d_ws;  // [B][2][32] u64

    // zero the sync slots (poison 0xAA.. would alias step tag 1365)
    hipMemsetAsync(d_ws, 0, (size_t)B * 2 * 32 * sizeof(unsigned long long), stream);

    fps_kernel<<<B * NPART, TPB, 0, stream>>>(xyz, centers, slots);
    knn_kernel<<<(B * S) / 4, 256, 0, stream>>>(xyz, centers, out);
}

// Round 7
// 2928.249 us; speedup vs baseline: 6.2631x; 6.2631x over previous
//
#include <hip/hip_runtime.h>

#define B 8
#define N 8192
#define S 2048
#define K 32
#define TPB 1024         // FPS threads/block (16 waves)
#define PPT 8            // contiguous points per thread: gid = t*8 + i
#define NPAIR (PPT / 2)

typedef float v2f __attribute__((ext_vector_type(2)));

// Exact (no-FMA, left-to-right) squared distance to match numpy fp32:
// ((dx*dx + dy*dy) + dz*dz). FPS argmax is a chaotic recurrence; any ulp
// difference diverges the center sequence. Verified absmax==0 (R1-R6).
__device__ __forceinline__ float sqdist3(float ax, float ay, float az,
                                         float bx, float by, float bz) {
    float dx = ax - bx, dy = ay - by, dz = az - bz;
    return __fadd_rn(__fadd_rn(__fmul_rn(dx, dx), __fmul_rn(dy, dy)),
                     __fmul_rn(dz, dz));
}

template <int CTRL>
__device__ __forceinline__ float dpp_fmax(float v) {
    const int iv = __float_as_int(v);
    const int sh = __builtin_amdgcn_update_dpp(iv, iv, CTRL, 0xF, 0xF, false);
    return fmaxf(v, __int_as_float(sh));
}
__device__ __forceinline__ float wave_fmax_dpp(float v) {
    v = dpp_fmax<0x111>(v);  // row_shr:1
    v = dpp_fmax<0x112>(v);  // row_shr:2
    v = dpp_fmax<0x114>(v);  // row_shr:4
    v = dpp_fmax<0x118>(v);  // row_shr:8
    v = dpp_fmax<0x142>(v);  // row_bcast:15
    v = dpp_fmax<0x143>(v);  // row_bcast:31 -> lane 63 = wave max
    return __int_as_float(__builtin_amdgcn_readlane(__float_as_int(v), 63));
}

// ---------------------------------------------------------------------------
// FPS: one block per batch (R6 proved cross-CU per-step sync is ~10x worse),
// 1024 threads, 8 CONTIGUOUS points/thread. PPT=8 keeps persistent arrays at
// 32 floats -> real VGPRs (R1's PPT=8 config allocated 40 VGPRs; the PPT=16
// configs allocated 68-72 for >=64 floats of arrays -> array traffic through
// AGPR moves, ~2x issue inflation, launch_bounds didn't move it).
// Packed-pair v2f math (fp contract OFF) -> v_pk_{add,mul}_f32 halves the
// bulk issue; per-half rounding == scalar, so selection is bit-identical.
// One barrier/step; publish = float4 {wmax,x,y,z} per wave; cross-wave scan
// is lane-parallel: lane reads pub[lane&15], DPP max + ballot + 3 readlanes.
// Tie-break invariant everywhere: (max dist, then lowest gid).
// ---------------------------------------------------------------------------
__global__ __launch_bounds__(TPB, 4) void fps_kernel(const float* __restrict__ xyz,
                                                     float* __restrict__ centers) {
#pragma clang fp contract(off)
    const int b = blockIdx.x;
    const float* xb = xyz + (size_t)b * N * 3;
    const int t = threadIdx.x;
    const int wid = t >> 6;
    const int lane = t & 63;

    // load 8 contiguous points (24 floats = 6 float4, 96B*t -> 16B aligned),
    // deinterleave into packed pairs: X[j]=(x2j,x2j+1), etc.
    float raw[3 * PPT];
    {
        const float4* src = (const float4*)(xb + 3 * PPT * t);
#pragma unroll
        for (int i = 0; i < 3 * PPT / 4; ++i) {
            const float4 v = src[i];
            raw[4 * i + 0] = v.x; raw[4 * i + 1] = v.y;
            raw[4 * i + 2] = v.z; raw[4 * i + 3] = v.w;
        }
    }
    v2f X[NPAIR], Y[NPAIR], Z[NPAIR], MD[NPAIR];
#pragma unroll
    for (int j = 0; j < NPAIR; ++j) {
        X[j] = (v2f){raw[6 * j + 0], raw[6 * j + 3]};
        Y[j] = (v2f){raw[6 * j + 1], raw[6 * j + 4]};
        Z[j] = (v2f){raw[6 * j + 2], raw[6 * j + 5]};
        MD[j] = (v2f){INFINITY, INFINITY};
    }

    __shared__ float4 pub[2][16];       // per-wave {wmax, x, y, z}, dbuf
    __shared__ float cent[S * 3];       // centers staged in LDS (24 KB)

    // step 0: reference always picks point 0
    float px = xb[0], py = xb[1], pz = xb[2];
    if (t == 0) { cent[0] = px; cent[1] = py; cent[2] = pz; }

    for (int s = 1; s < S; ++s) {
        // --- packed update: D = (dx*dx + dy*dy) + dz*dz per half (pk ops
        //     round per-half exactly like scalar; contract(off) forbids fma)
        const v2f P_ = (v2f){px, px}, Q_ = (v2f){py, py}, R_ = (v2f){pz, pz};
        float tmax[NPAIR];
#pragma unroll
        for (int j = 0; j < NPAIR; ++j) {
            const v2f dx = X[j] - P_, dy = Y[j] - Q_, dz = Z[j] - R_;
            const v2f d = (dx * dx + dy * dy) + dz * dz;
            const v2f m = {fminf(MD[j].x, d.x), fminf(MD[j].y, d.y)};
            MD[j] = m;
            tmax[j] = fmaxf(m.x, m.y);
        }
#pragma unroll
        for (int st = 1; st < NPAIR; st <<= 1)
#pragma unroll
            for (int j = 0; j < NPAIR; j += 2 * st)
                tmax[j] = fmaxf(tmax[j], tmax[j + st]);
        const float best = tmax[0];

        // --- wave max (DPP) + first-lane tie-break via ballot (lowest lane
        //     == lowest gid: points are lane-contiguous)
        const float wmax = wave_fmax_dpp(best);
        const unsigned long long mb = __ballot(best == wmax);
        const int ol = (int)__builtin_ctzll(mb);

        // --- owner lane: ascending first-match re-derive (lowest i), publish
        const int pb = s & 1;
        if (lane == ol) {
            float wx = X[0].x, wy = Y[0].x, wz = Z[0].x;
            bool found = (MD[0].x == wmax);
#pragma unroll
            for (int j = 0; j < NPAIR; ++j) {
#pragma unroll
                for (int h = 0; h < 2; ++h) {
                    if (j == 0 && h == 0) continue;
                    const float mv = h ? MD[j].y : MD[j].x;
                    const bool hit = !found && (mv == wmax);
                    wx = hit ? (h ? X[j].y : X[j].x) : wx;
                    wy = hit ? (h ? Y[j].y : Y[j].x) : wy;
                    wz = hit ? (h ? Z[j].y : Z[j].x) : wz;
                    found = found || hit;
                }
            }
            pub[pb][wid] = make_float4(wmax, wx, wy, wz);
        }
        __syncthreads();                 // the ONLY barrier per step

        // --- lane-parallel scan of 16 wave winners: lane i reads slot i&15
        //     (lanes 0-15 cover all slots; ctz -> lowest wid on ties = lowest gid)
        const float4 v = pub[pb][lane & 15];
        const float gmax = wave_fmax_dpp(v.x);
        const unsigned long long gb = __ballot(v.x == gmax);
        const int gl = (int)__builtin_ctzll(gb);
        px = __int_as_float(__builtin_amdgcn_readlane(__float_as_int(v.y), gl));
        py = __int_as_float(__builtin_amdgcn_readlane(__float_as_int(v.z), gl));
        pz = __int_as_float(__builtin_amdgcn_readlane(__float_as_int(v.w), gl));

        if (t == 0) {
            cent[3 * s + 0] = px;
            cent[3 * s + 1] = py;
            cent[3 * s + 2] = pz;
        }
    }

    // --- coalesced dump of centers LDS -> global (S*3 = 6144 = 1024*6)
    __syncthreads();
    float* cb = centers + (size_t)b * S * 3;
#pragma unroll
    for (int j = 0; j < (S * 3) / TPB; ++j) {
        const int idx = t + TPB * j;
        cb[idx] = cent[idx];
    }
}

// ---------------------------------------------------------------------------
// KNN + gather: one wave per center. Top-32 held SORTED across lanes 0..31 as
// packed u64 (dist_bits<<32 | idx) -> lexicographic (d, idx) order == stable
// top_k tie semantics. Insert = wave-wide shfl_up shift (O(1) per insert).
// ---------------------------------------------------------------------------
__global__ __launch_bounds__(256) void knn_kernel(const float* __restrict__ xyz,
                                                  const float* __restrict__ centers,
                                                  float* __restrict__ out) {
    const int gw = (int)((blockIdx.x * blockDim.x + threadIdx.x) >> 6);
    const int lane = (int)(threadIdx.x & 63);
    const int b = gw >> 11;        // gw / S
    const int s = gw & (S - 1);
    const float* xb = xyz + (size_t)b * N * 3;
    const float* c = centers + (size_t)(b * S + s) * 3;
    const float cx = c[0], cy = c[1], cz = c[2];

    unsigned long long P = ~0ULL;     // lanes 0..31: sorted top-32 (asc)
    unsigned long long tau = ~0ULL;   // current worst kept = P at lane 31

    for (int i = 0; i < N / 64; ++i) {
        const int p = (i << 6) + lane;
        const float* q = xb + 3 * p;
        const float d = sqdist3(q[0], q[1], q[2], cx, cy, cz);
        const unsigned long long cand =
            ((unsigned long long)__float_as_uint(d) << 32) | (unsigned)p;
        bool alive = cand < tau;
        unsigned long long mask = __ballot(alive);
        while (mask) {
            const int src = __builtin_ctzll(mask);
            const unsigned long long bc = __shfl(cand, src);
            unsigned long long up = __shfl_up(P, 1);
            if (lane == 0) up = bc;
            const bool gt = P > bc;  // strict: bc < tau guarantees lane31 evicts
            const unsigned long long shifted = (up > bc) ? up : bc;
            P = gt ? shifted : P;
            tau = __shfl(P, 31);
            if (lane == src) alive = false;
            alive = alive && (cand < tau);
            mask = __ballot(alive);
        }
    }

    // epilogue: lane k = k-th nearest (ascending d, ties by index = top_k order)
    if (lane < K) {
        const unsigned nidx = (unsigned)P;
        const float* q = xb + 3 * nidx;
        float* o = out + ((size_t)(b * S + s) * K + lane) * 3;
        o[0] = q[0] - cx;
        o[1] = q[1] - cy;
        o[2] = q[2] - cz;
    }
}

extern "C" void kernel_launch(void* const* d_in, const int* in_sizes, int n_in,
                              void* d_out, int out_size, void* d_ws, size_t ws_size,
                              hipStream_t stream) {
    const float* xyz = (const float*)d_in[0];
    float* out = (float*)d_out;                         // neighborhood [B,S,K,3]
    float* centers = out + (size_t)B * S * K * 3;       // centers [B,S,3]

    fps_kernel<<<B, TPB, 0, stream>>>(xyz, centers);
    knn_kernel<<<(B * S) / 4, 256, 0, stream>>>(xyz, centers, out);
}

// Round 8
// 2704.449 us; speedup vs baseline: 6.7814x; 1.0828x over previous
//
#include <hip/hip_runtime.h>

#define B 8
#define N 8192
#define S 2048
#define K 32
#define TPB 1024          // block size (16 waves); FPS uses 8 active waves
#define ACT 512           // active FPS threads
#define PPT (N / ACT)     // 16 contiguous points per active thread
#define NCHUNK 31         // worker chunks per batch
#define CHUNK_STEP 128    // FPS publish cadence (centers per release)

// Exact (no-FMA, left-to-right) squared distance to match numpy fp32:
// ((dx*dx + dy*dy) + dz*dz). FPS argmax is a chaotic recurrence; any ulp
// difference diverges the center sequence. Verified absmax==0 (R1-R7).
__device__ __forceinline__ float sqdist3(float ax, float ay, float az,
                                         float bx, float by, float bz) {
    float dx = ax - bx, dy = ay - by, dz = az - bz;
    return __fadd_rn(__fadd_rn(__fmul_rn(dx, dx), __fmul_rn(dy, dy)),
                     __fmul_rn(dz, dz));
}

template <int CTRL>
__device__ __forceinline__ float dpp_fmax(float v) {
    const int iv = __float_as_int(v);
    const int sh = __builtin_amdgcn_update_dpp(iv, iv, CTRL, 0xF, 0xF, false);
    return fmaxf(v, __int_as_float(sh));
}
__device__ __forceinline__ float wave_fmax_dpp(float v) {
    v = dpp_fmax<0x111>(v);  // row_shr:1
    v = dpp_fmax<0x112>(v);  // row_shr:2
    v = dpp_fmax<0x114>(v);  // row_shr:4
    v = dpp_fmax<0x118>(v);  // row_shr:8
    v = dpp_fmax<0x142>(v);  // row_bcast:15
    v = dpp_fmax<0x143>(v);  // row_bcast:31 -> lane 63 = wave max
    return __int_as_float(__builtin_amdgcn_readlane(__float_as_int(v), 63));
}

// ---------------------------------------------------------------------------
// Fused producer-consumer kernel, 256 blocks == 256 CUs (all resident; no
// dispatch-order assumption needed for progress: workers only sleep-spin on
// progress[], FPS blocks are guaranteed resident so progress always advances).
//  - blocks 0..7   : FPS producer for batch b (R4-verified structure, best
//                    measured config: 512 active threads, PPT=16, one barrier
//                    per step). Centers staged in LDS; every 128 steps the
//                    block copies the chunk to global, drains it with a
//                    barrier, then t0 agent-RELEASE-stores progress[b]
//                    (emits L2 writeback -> cross-XCD safe per G16).
//  - blocks 8..255 : 31 worker blocks per batch (b = (blk-8)&7 -> same XCD
//                    as FPS block b under %8 round-robin; locality only).
//                    t0 sleep-spins (agent-ACQUIRE load + s_sleep backoff,
//                    ~1 poll/1.7us/block -> negligible L2 traffic) until the
//                    block's chunk [c0,c1) of centers is published, then its
//                    16 waves run the verified wave-KNN (strided over chunk).
// FPS VGPR (>64, PPT=16 arrays) + 1024 threads -> 16 waves/CU cap -> exactly
// 1 block/CU: FPS blocks never share a CU with workers.
// Tie-break invariants unchanged: FPS (max dist, min gid); KNN (d, idx)
// lexicographic == stable top_k. absmax must stay 0.
// ---------------------------------------------------------------------------
__global__ __launch_bounds__(TPB, 4) void fused_kernel(
    const float* __restrict__ xyz, float* __restrict__ out,
    float* __restrict__ centers, unsigned* __restrict__ progress) {
    const int blk = blockIdx.x;
    const int t = threadIdx.x;

    if (blk < B) {
        // =================== FPS producer (R4 structure) ===================
        const int b = blk;
        const float* xb = xyz + (size_t)b * N * 3;
        float* cb = centers + (size_t)b * S * 3;
        const bool act = t < ACT;          // wave-uniform (512 = 8 full waves)
        const int wid = t >> 6;
        const int lane = t & 63;

        float x[PPT], y[PPT], z[PPT], md[PPT];
        if (act) {
            float raw[3 * PPT];
            const float4* src = (const float4*)(xb + 3 * PPT * t);
#pragma unroll
            for (int i = 0; i < 3 * PPT / 4; ++i) {
                const float4 v = src[i];
                raw[4 * i + 0] = v.x; raw[4 * i + 1] = v.y;
                raw[4 * i + 2] = v.z; raw[4 * i + 3] = v.w;
            }
#pragma unroll
            for (int i = 0; i < PPT; ++i) {
                x[i] = raw[3 * i + 0];
                y[i] = raw[3 * i + 1];
                z[i] = raw[3 * i + 2];
                md[i] = INFINITY;
            }
        }

        __shared__ float4 pub[2][8];       // per-wave {wmax,x,y,z}, dbuf
        __shared__ float cent[S * 3];      // centers staged in LDS (24 KB)

        float px = xb[0], py = xb[1], pz = xb[2];   // step 0: point 0
        if (t == 0) { cent[0] = px; cent[1] = py; cent[2] = pz; }

        for (int s = 1; s < S; ++s) {
            const int pb = s & 1;
            if (act) {
                // local update; tree max (no index tracking in hot path)
                float m[PPT];
#pragma unroll
                for (int i = 0; i < PPT; ++i) {
                    const float d = sqdist3(x[i], y[i], z[i], px, py, pz);
                    m[i] = fminf(md[i], d);
                    md[i] = m[i];
                }
#pragma unroll
                for (int st = 1; st < PPT; st <<= 1)
#pragma unroll
                    for (int i = 0; i < PPT; i += 2 * st)
                        m[i] = fmaxf(m[i], m[i + st]);
                const float best = m[0];

                // wave max (DPP) + first-lane tie-break via ballot
                const float wmax = wave_fmax_dpp(best);
                const unsigned long long mb = __ballot(best == wmax);
                const int ol = (int)__builtin_ctzll(mb);

                // owner: re-derive lowest i (descending overwrite), publish
                if (lane == ol) {
                    int bi = 0;
#pragma unroll
                    for (int i = PPT - 1; i >= 0; --i)
                        if (md[i] == wmax) bi = i;
                    pub[pb][wid] = make_float4(wmax, x[bi], y[bi], z[bi]);
                }
            }
            __syncthreads();               // the ONLY per-step barrier

            if (act) {
                // serial scan of 8 wave winners (strict > -> lowest wid ties)
                float4 v0 = pub[pb][0];
                float gmax = v0.x;
                px = v0.y; py = v0.z; pz = v0.w;
#pragma unroll
                for (int w = 1; w < 8; ++w) {
                    const float4 u = pub[pb][w];
                    const bool g = u.x > gmax;
                    gmax = g ? u.x : gmax;
                    px = g ? u.y : px;
                    py = g ? u.z : py;
                    pz = g ? u.w : pz;
                }
                if (t == 0) {
                    cent[3 * s + 0] = px;
                    cent[3 * s + 1] = py;
                    cent[3 * s + 2] = pz;
                }
            }

            // ---- chunk publish: copy 128 centers LDS->global, drain, release
            if ((s & (CHUNK_STEP - 1)) == (CHUNK_STEP - 1)) {
                __syncthreads();           // t0's cent[3s] visible to copiers
                const int base = 3 * (s - (CHUNK_STEP - 1));
                if (t < 3 * CHUNK_STEP) cb[base + t] = cent[base + t];
                __syncthreads();           // drain copiers' stores (vmcnt0)
                if (t == 0)
                    __hip_atomic_store(&progress[b], (unsigned)(s + 1),
                                       __ATOMIC_RELEASE, __HIP_MEMORY_SCOPE_AGENT);
            }
        }
    } else {
        // ======================= KNN worker ================================
        const int w = blk - B;
        const int b = w & 7;               // same XCD as FPS block b (%8 rr)
        const int chunk = w >> 3;          // 0..30
        const int c0 = (S * chunk) / NCHUNK;
        const int c1 = (S * (chunk + 1)) / NCHUNK;

        if (t == 0) {
            while ((int)__hip_atomic_load(&progress[b], __ATOMIC_ACQUIRE,
                                          __HIP_MEMORY_SCOPE_AGENT) < c1)
                __builtin_amdgcn_s_sleep(32);   // ~2k cyc backoff
        }
        __syncthreads();

        const int wv = t >> 6;
        const int lane = t & 63;
        const float* xb = xyz + (size_t)b * N * 3;

        for (int s = c0 + wv; s < c1; s += TPB / 64) {
            const float* c = centers + (size_t)(b * S + s) * 3;
            const float cx = c[0], cy = c[1], cz = c[2];

            unsigned long long P = ~0ULL;   // lanes 0..31: sorted top-32 (asc)
            unsigned long long tau = ~0ULL;

            for (int i = 0; i < N / 64; ++i) {
                const int p = (i << 6) + lane;
                const float* q = xb + 3 * p;
                const float d = sqdist3(q[0], q[1], q[2], cx, cy, cz);
                const unsigned long long cand =
                    ((unsigned long long)__float_as_uint(d) << 32) | (unsigned)p;
                bool alive = cand < tau;
                unsigned long long mask = __ballot(alive);
                while (mask) {
                    const int src = __builtin_ctzll(mask);
                    const unsigned long long bc = __shfl(cand, src);
                    unsigned long long up = __shfl_up(P, 1);
                    if (lane == 0) up = bc;
                    const bool gt = P > bc;
                    const unsigned long long shifted = (up > bc) ? up : bc;
                    P = gt ? shifted : P;
                    tau = __shfl(P, 31);
                    if (lane == src) alive = false;
                    alive = alive && (cand < tau);
                    mask = __ballot(alive);
                }
            }

            if (lane < K) {
                const unsigned nidx = (unsigned)P;
                const float* q = xb + 3 * nidx;
                float* o = out + ((size_t)(b * S + s) * K + lane) * 3;
                o[0] = q[0] - cx;
                o[1] = q[1] - cy;
                o[2] = q[2] - cz;
            }
        }
    }
}

extern "C" void kernel_launch(void* const* d_in, const int* in_sizes, int n_in,
                              void* d_out, int out_size, void* d_ws, size_t ws_size,
                              hipStream_t stream) {
    const float* xyz = (const float*)d_in[0];
    float* out = (float*)d_out;                         // neighborhood [B,S,K,3]
    float* centers = out + (size_t)B * S * K * 3;       // centers [B,S,3]
    unsigned* progress = (unsigned*)d_ws;               // [B] centers-ready count

    // d_ws is poisoned 0xAA before every timed launch -> must zero progress
    hipMemsetAsync(d_ws, 0, B * sizeof(unsigned), stream);

    fused_kernel<<<8 + NCHUNK * B, TPB, 0, stream>>>(xyz, out, centers, progress);
}

// Round 9
// 2331.003 us; speedup vs baseline: 7.8678x; 1.1602x over previous
//
#include <hip/hip_runtime.h>

#define B 8
#define N 8192
#define S 2048
#define K 32
#define TPB 512           // all blocks: 8 waves
#define PPT (N / TPB)     // 16 contiguous points per FPS thread
#define CHUNK_STEP 128    // FPS publish cadence
#define WPB 31            // worker blocks per batch
#define WVB (WPB * 8)     // 248 KNN waves per batch (stride)

// Exact (no-FMA, left-to-right) squared distance to match numpy fp32:
// ((dx*dx + dy*dy) + dz*dz). FPS argmax is a chaotic recurrence; any ulp
// difference diverges the center sequence. Verified absmax==0 (R1-R8).
__device__ __forceinline__ float sqdist3(float ax, float ay, float az,
                                         float bx, float by, float bz) {
    float dx = ax - bx, dy = ay - by, dz = az - bz;
    return __fadd_rn(__fadd_rn(__fmul_rn(dx, dx), __fmul_rn(dy, dy)),
                     __fmul_rn(dz, dz));
}

template <int CTRL>
__device__ __forceinline__ float dpp_fmax(float v) {
    const int iv = __float_as_int(v);
    const int sh = __builtin_amdgcn_update_dpp(iv, iv, CTRL, 0xF, 0xF, false);
    return fmaxf(v, __int_as_float(sh));
}
__device__ __forceinline__ float wave_fmax_dpp(float v) {
    v = dpp_fmax<0x111>(v);  // row_shr:1
    v = dpp_fmax<0x112>(v);  // row_shr:2
    v = dpp_fmax<0x114>(v);  // row_shr:4
    v = dpp_fmax<0x118>(v);  // row_shr:8
    v = dpp_fmax<0x142>(v);  // row_bcast:15
    v = dpp_fmax<0x143>(v);  // row_bcast:31 -> lane 63 = wave max
    return __int_as_float(__builtin_amdgcn_readlane(__float_as_int(v), 63));
}

// ---------------------------------------------------------------------------
// Fused producer-consumer, 256 blocks x 512 threads (2048 waves << 8192 wave
// slots -> all blocks resident no matter the placement; workers wait only on
// FPS progress, FPS waits on nobody -> deadlock-free).
//  - blocks 0..7: FPS producer = R4's best measured config verbatim (8 waves
//    all active, PPT=16, one barrier/step, zero global ops in the step body).
//    Every 128 steps: barrier, copy chunk LDS->global, barrier (drains vmcnt),
//    t0 agent-RELEASE store of progress[b] (L2 writeback -> cross-XCD safe).
//  - blocks 8..255: 31 worker blocks/batch. STRIDED center assignment: per
//    batch, wave w handles centers w, w+248, ... in order, waiting per-center
//    on progress[b] > s (register-cached; agent-ACQUIRE broadcast load +
//    s_sleep backoff). After the final publish the last 128 centers sit <=1
//    per wave -> tail ~= one KNN scan (~15us), vs R8's ~150us chunk tail.
// Tie-break invariants unchanged: FPS (max dist, min gid); KNN (d, idx)
// lexicographic == stable top_k. absmax must stay 0.
// ---------------------------------------------------------------------------
__global__ __launch_bounds__(TPB, 2) void fused_kernel(
    const float* __restrict__ xyz, float* __restrict__ out,
    float* __restrict__ centers, unsigned* __restrict__ progress) {
    const int blk = blockIdx.x;
    const int t = threadIdx.x;
    const int lane = t & 63;

    if (blk < B) {
        // =================== FPS producer (R4 structure) ===================
        const int b = blk;
        const float* xb = xyz + (size_t)b * N * 3;
        float* cb = centers + (size_t)b * S * 3;
        const int wid = t >> 6;

        float x[PPT], y[PPT], z[PPT], md[PPT];
        {
            float raw[3 * PPT];
            const float4* src = (const float4*)(xb + 3 * PPT * t);
#pragma unroll
            for (int i = 0; i < 3 * PPT / 4; ++i) {
                const float4 v = src[i];
                raw[4 * i + 0] = v.x; raw[4 * i + 1] = v.y;
                raw[4 * i + 2] = v.z; raw[4 * i + 3] = v.w;
            }
#pragma unroll
            for (int i = 0; i < PPT; ++i) {
                x[i] = raw[3 * i + 0];
                y[i] = raw[3 * i + 1];
                z[i] = raw[3 * i + 2];
                md[i] = INFINITY;
            }
        }

        __shared__ float4 pub[2][8];       // per-wave {wmax,x,y,z}, dbuf
        __shared__ float cent[S * 3];      // centers staged in LDS (24 KB)

        float px = xb[0], py = xb[1], pz = xb[2];   // step 0: point 0
        if (t == 0) { cent[0] = px; cent[1] = py; cent[2] = pz; }

        for (int s = 1; s < S; ++s) {
            // local update; tree max (no index tracking in hot path)
            float m[PPT];
#pragma unroll
            for (int i = 0; i < PPT; ++i) {
                const float d = sqdist3(x[i], y[i], z[i], px, py, pz);
                m[i] = fminf(md[i], d);
                md[i] = m[i];
            }
#pragma unroll
            for (int st = 1; st < PPT; st <<= 1)
#pragma unroll
                for (int i = 0; i < PPT; i += 2 * st)
                    m[i] = fmaxf(m[i], m[i + st]);
            const float best = m[0];

            // wave max (DPP) + first-lane tie-break via ballot
            const float wmax = wave_fmax_dpp(best);
            const unsigned long long mb = __ballot(best == wmax);
            const int ol = (int)__builtin_ctzll(mb);

            // owner: re-derive lowest i (descending overwrite), publish
            const int pb = s & 1;
            if (lane == ol) {
                int bi = 0;
#pragma unroll
                for (int i = PPT - 1; i >= 0; --i)
                    if (md[i] == wmax) bi = i;
                pub[pb][wid] = make_float4(wmax, x[bi], y[bi], z[bi]);
            }
            __syncthreads();               // the ONLY per-step barrier

            // serial scan of 8 wave winners (strict > -> lowest wid on ties)
            float4 v0 = pub[pb][0];
            float gmax = v0.x;
            px = v0.y; py = v0.z; pz = v0.w;
#pragma unroll
            for (int w = 1; w < 8; ++w) {
                const float4 u = pub[pb][w];
                const bool g = u.x > gmax;
                gmax = g ? u.x : gmax;
                px = g ? u.y : px;
                py = g ? u.z : py;
                pz = g ? u.w : pz;
            }
            if (t == 0) {
                cent[3 * s + 0] = px;
                cent[3 * s + 1] = py;
                cent[3 * s + 2] = pz;
            }

            // ---- chunk publish: barrier, copy, barrier (vmcnt drain), release
            if ((s & (CHUNK_STEP - 1)) == (CHUNK_STEP - 1)) {
                __syncthreads();           // t0's cent[3s] visible to copiers
                const int base = 3 * (s - (CHUNK_STEP - 1));
                if (t < 3 * CHUNK_STEP) cb[base + t] = cent[base + t];
                __syncthreads();           // drains copiers' stores (vmcnt0)
                if (t == 0)
                    __hip_atomic_store(&progress[b], (unsigned)(s + 1),
                                       __ATOMIC_RELEASE, __HIP_MEMORY_SCOPE_AGENT);
            }
        }
    } else {
        // ======================= KNN workers ===============================
        const int w = blk - B;
        const int b = w & 7;               // same XCD as FPS block b (%8 rr)
        const int wchunk = w >> 3;         // 0..30
        const int waveid = wchunk * 8 + (t >> 6);   // 0..247 within batch
        const float* xb = xyz + (size_t)b * N * 3;

        unsigned seen = 0;                 // register-cached progress[b]
        for (int s = waveid; s < S; s += WVB) {
            // wait until progress[b] > s (all lanes load same line ->
            // broadcast; ACQUIRE invalidates L1 so center reads are fresh)
            while (seen <= (unsigned)s) {
                seen = __hip_atomic_load(&progress[b], __ATOMIC_ACQUIRE,
                                         __HIP_MEMORY_SCOPE_AGENT);
                if (seen <= (unsigned)s) __builtin_amdgcn_s_sleep(64);
            }

            const float* c = centers + (size_t)(b * S + s) * 3;
            const float cx = c[0], cy = c[1], cz = c[2];

            unsigned long long P = ~0ULL;   // lanes 0..31: sorted top-32 (asc)
            unsigned long long tau = ~0ULL;

            for (int i = 0; i < N / 64; ++i) {
                const int p = (i << 6) + lane;
                const float* q = xb + 3 * p;
                const float d = sqdist3(q[0], q[1], q[2], cx, cy, cz);
                const unsigned long long cand =
                    ((unsigned long long)__float_as_uint(d) << 32) | (unsigned)p;
                bool alive = cand < tau;
                unsigned long long mask = __ballot(alive);
                while (mask) {
                    const int src = __builtin_ctzll(mask);
                    const unsigned long long bc = __shfl(cand, src);
                    unsigned long long up = __shfl_up(P, 1);
                    if (lane == 0) up = bc;
                    const bool gt = P > bc;
                    const unsigned long long shifted = (up > bc) ? up : bc;
                    P = gt ? shifted : P;
                    tau = __shfl(P, 31);
                    if (lane == src) alive = false;
                    alive = alive && (cand < tau);
                    mask = __ballot(alive);
                }
            }

            if (lane < K) {
                const unsigned nidx = (unsigned)P;
                const float* q = xb + 3 * nidx;
                float* o = out + ((size_t)(b * S + s) * K + lane) * 3;
                o[0] = q[0] - cx;
                o[1] = q[1] - cy;
                o[2] = q[2] - cz;
            }
        }
    }
}

extern "C" void kernel_launch(void* const* d_in, const int* in_sizes, int n_in,
                              void* d_out, int out_size, void* d_ws, size_t ws_size,
                              hipStream_t stream) {
    const float* xyz = (const float*)d_in[0];
    float* out = (float*)d_out;                         // neighborhood [B,S,K,3]
    float* centers = out + (size_t)B * S * K * 3;       // centers [B,S,3]
    unsigned* progress = (unsigned*)d_ws;               // [B] centers-ready count

    // d_ws is poisoned 0xAA before every timed launch -> must zero progress
    hipMemsetAsync(d_ws, 0, B * sizeof(unsigned), stream);

    fused_kernel<<<B + WPB * B, TPB, 0, stream>>>(xyz, out, centers, progress);
}